// Round 12
// baseline (737.018 us; speedup 1.0000x reference)
//
#include <hip/hip_runtime.h>
#include <stdint.h>

#define THREADS 256

typedef short bf16x8 __attribute__((ext_vector_type(8)));
typedef float f32x4 __attribute__((ext_vector_type(4)));
typedef unsigned uint2_ __attribute__((ext_vector_type(2)));

__device__ __forceinline__ unsigned short f2bf(float v) {
  unsigned u = __builtin_bit_cast(unsigned, v);
  u = (u + 0x7fff + ((u >> 16) & 1)) >> 16;
  return (unsigned short)u;
}
__device__ __forceinline__ float bf2f(unsigned short h) {
  return __builtin_bit_cast(float, (unsigned)h << 16);
}
__device__ __forceinline__ float fast_tanh(float x) {
  return 1.f - 2.f / (__expf(2.f * x) + 1.f);
}

__device__ __forceinline__ int xcd_swizzle(int wg, int nwg) {
  const int q = nwg >> 3, rr = nwg & 7;
  const int xcd = wg & 7, l = wg >> 3;
  return (xcd < rr ? xcd * (q + 1) : rr * (q + 1) + (xcd - rr) * q) + l;
}

// ---------------------------------------------------------------------------
// w1 transpose: (32, 45) -> (45, 32) fp32, for wave-uniform scalar loads.
// ---------------------------------------------------------------------------
__global__ void pack_w1t(const float* __restrict__ w1, float* __restrict__ w1t) {
  int idx = blockIdx.x * THREADS + threadIdx.x;
  if (idx >= 45 * 32) return;
  int t = idx >> 5, co = idx & 31;
  w1t[t * 32 + co] = w1[co * 45 + t];
}

// ---------------------------------------------------------------------------
// conv1 fused: x NCHW f32 -> out (29*29, Bc, 32) bf16, k3 s2, tanh.
// Block = 2 oh-rows of one sample. Wave = co-octet (weights wave-uniform),
// lane = position, acc[8] in VGPRs.
// ---------------------------------------------------------------------------
__global__ void __launch_bounds__(256) conv1_direct(
    const float* __restrict__ x, const float* __restrict__ w1t,
    const float* __restrict__ bias, unsigned short* __restrict__ out, int Bc,
    int bstart) {
  constexpr int CI = 5, CO = 32, IH = 60, IW = 60, OH = 29, OW = 29;
  constexpr int RPB = 2, NRB = 15;

  __shared__ float xs[CI * 5 * 60];  // 6000 B

  const int tid = threadIdx.x;
  const int b = blockIdx.x / NRB;
  const int qb = blockIdx.x % NRB;
  const int oh0 = qb * RPB;
  const int rows = min(RPB, OH - oh0);
  const int ih0 = oh0 * 2;
  const int ihn = rows * 2 + 1;

  const float* xp = x + (size_t)(bstart + b) * (CI * IH * IW);

  const int nf4 = CI * ihn * 15;
  for (int i = tid; i < nf4; i += 256) {
    int col = i % 15;
    int row = i / 15;
    int ci = row / ihn, r = row % ihn;
    ((float4*)xs)[row * 15 + col] = ((const float4*)xp)[(ci * IH + ih0 + r) * 15 + col];
  }
  __syncthreads();

  const int lane = tid & 63;
  const int wu = __builtin_amdgcn_readfirstlane(tid >> 6);
  if (lane >= rows * OW) return;
  const int r = lane / OW, c = lane % OW;
  const int base = (r * 2) * 60 + c * 2;
  const int cstr = ihn * 60;

  float acc[8];
#pragma unroll
  for (int j = 0; j < 8; j++) acc[j] = bias[wu * 8 + j];

#pragma unroll
  for (int ci = 0; ci < CI; ci++)
#pragma unroll
    for (int kh = 0; kh < 3; kh++)
#pragma unroll
      for (int kw = 0; kw < 3; kw++) {
        const float v = xs[ci * cstr + base + kh * 60 + kw];
        const float* wt = w1t + ((ci * 3 + kh) * 3 + kw) * 32 + wu * 8;
#pragma unroll
        for (int j = 0; j < 8; j++) acc[j] = fmaf(v, wt[j], acc[j]);
      }

  const int p = (oh0 + r) * OW + c;
  bf16x8 o;
#pragma unroll
  for (int j = 0; j < 8; j++) o[j] = (short)f2bf(fast_tanh(acc[j]));
  *(bf16x8*)(out + ((size_t)p * Bc + b) * CO + wu * 8) = o;
}

// ---------------------------------------------------------------------------
// Weight pre-pack into MFMA A-fragment order (bf16).
// dst wp: flat[pos][s][mt][lane][e], value = W[co=mt*16+(lane&15)]
//                                          [k = s*32 + (lane>>4)*8 + e]
// k-order: k = (kh*KS+kw)*CI + ci  (ci innermost).
// ---------------------------------------------------------------------------
template <int CI, int KS>
__global__ void __launch_bounds__(THREADS) pack_w(const float* __restrict__ w,
                                                  unsigned short* __restrict__ wp,
                                                  int npos) {
  constexpr int K = CI * KS * KS;
  constexpr int S = K / 32;
  int idx = blockIdx.x * THREADS + threadIdx.x;
  int total = npos * S * 2048;
  if (idx >= total) return;
  int e = idx & 7;
  int lane = (idx >> 3) & 63;
  int mt = (idx >> 9) & 3;
  int rest = idx >> 11;  // pos*S + s
  int s = rest % S, pos = rest / S;
  int co = mt * 16 + (lane & 15);
  int k = s * 32 + (lane >> 4) * 8 + e;
  int tap = k / CI, ci = k % CI;
  int kh = tap / KS, kw = tap % KS;
  float v = w[((((size_t)pos * 64 + co) * CI + ci) * KS + kh) * KS + kw];
  wp[idx] = f2bf(v);
}

// ---------------------------------------------------------------------------
// MFMA conv v6: barrier-free, zero-LDS, EXPLICIT 2-deep software pipeline.
// X: (IH*IW, Bc, CI)  Wp: packed  Y: (OH*OW, Bc, 64)
// Ping-pong fragment sets (afA,bfA)/(afB,bfB): step s+1's loads issue before
// step s's MFMA cluster -> latency hides under MFMA + other waves.
// Block = 4 waves: BW batch-split x CW=4/BW co-split; wave = MT(=BW) 16-co
// tiles x NJ 16-batch groups. Dense: pos-minor grid (X L2 locality);
// local: pos-major (W L2 locality). Bijective XCD swizzle.
// ---------------------------------------------------------------------------
template <int CI, int IH, int IW, int OH, int OW, int KS, int ST, bool LOCAL, int BW,
          int NJ>
__global__ void __launch_bounds__(256) conv_mfma(
    const unsigned short* __restrict__ X, const unsigned short* __restrict__ Wp,
    const float* __restrict__ bias, unsigned short* __restrict__ Y, int Bc) {
  constexpr int S = CI * KS * KS / 32;
  constexpr int NPOS = OH * OW;
  constexpr int MT = BW;           // 16-co tiles per wave
  constexpr int BPB = BW * NJ * 16;  // batch per block

  const int tid = threadIdx.x;
  const int lane = tid & 63;
  const int wu = tid >> 6;
  const int n = lane & 15, g = lane >> 4;
  const int bw = wu % BW, cw = wu / BW;

  const int nbt = Bc / BPB;
  int wg = xcd_swizzle(blockIdx.x, gridDim.x);
  int pos, btile;
  if (LOCAL) {  // pos-major: same-pos blocks contiguous -> W L2 locality
    btile = wg % nbt;
    pos = wg / nbt;
  } else {  // pos-minor: neighbor-pos blocks contiguous -> X L2 locality
    pos = wg % NPOS;
    btile = wg / NPOS;
  }
  const int oh = pos / OW, ow = pos % OW;
  const int b0 = btile * BPB + bw * (NJ * 16);
  const int bA = b0 + n;

  const unsigned short* Wpp = Wp + (LOCAL ? (size_t)pos * (S * 2048) : 0);

  auto LD = [&](int s, bf16x8* af, bf16x8* bf) {
    const int tap = (s * 32) / CI;
    const int ci0 = (s * 32) % CI + g * 8;
    const int kh = tap / KS, kw = tap % KS;
    const int pin = (oh * ST + kh) * IW + (ow * ST + kw);
    const unsigned short* xb = X + ((size_t)pin * Bc + bA) * CI + ci0;
#pragma unroll
    for (int j = 0; j < NJ; j++) bf[j] = *(const bf16x8*)(xb + j * 16 * CI);
#pragma unroll
    for (int mt = 0; mt < MT; mt++)
      af[mt] =
          *(const bf16x8*)(Wpp + ((size_t)((s * 4 + cw * MT + mt) * 64 + lane) << 3));
  };

  f32x4 acc[MT][NJ] = {};
  auto MM = [&](bf16x8* af, bf16x8* bf) {
#pragma unroll
    for (int mt = 0; mt < MT; mt++)
#pragma unroll
      for (int j = 0; j < NJ; j++)
        acc[mt][j] =
            __builtin_amdgcn_mfma_f32_16x16x32_bf16(af[mt], bf[j], acc[mt][j], 0, 0, 0);
  };

  bf16x8 afA[MT], bfA[NJ], afB[MT], bfB[NJ];
  LD(0, afA, bfA);
  for (int s = 0; s < S; s += 2) {
    if (s + 1 < S) LD(s + 1, afB, bfB);
    MM(afA, bfA);
    if (s + 2 < S) LD(s + 2, afA, bfA);
    if (s + 1 < S) MM(afB, bfB);
  }

  // epilogue: D col=lane&15 (batch), row=(lane>>4)*4+reg (co)
#pragma unroll
  for (int mt = 0; mt < MT; mt++) {
#pragma unroll
    for (int j = 0; j < NJ; j++) {
      unsigned short o[4];
#pragma unroll
      for (int r = 0; r < 4; r++) {
        const int co = (cw * MT + mt) * 16 + g * 4 + r;
        o[r] = f2bf(fast_tanh(acc[mt][j][r] +
                              (LOCAL ? bias[pos * 64 + co] : bias[co])));
      }
      const int b = b0 + j * 16 + n;
      uint2_ pk;
      pk[0] = (unsigned)o[0] | ((unsigned)o[1] << 16);
      pk[1] = (unsigned)o[2] | ((unsigned)o[3] << 16);
      *(uint2_*)(Y + ((size_t)pos * Bc + b) * 64 + (cw * MT + mt) * 16 + g * 4) = pk;
    }
  }
}

// ---------------------------------------------------------------------------
// Head: h5 (9, Bc, 64) bf16; f = co*9 + pos. concat info(8), linear, softmax.
// ---------------------------------------------------------------------------
__global__ void head_k(const unsigned short* __restrict__ h5,
                       const float* __restrict__ info, const float* __restrict__ hw,
                       const float* __restrict__ hb, float* __restrict__ out, int Bc,
                       int bstart) {
  int b = blockIdx.x * THREADS + threadIdx.x;
  if (b >= Bc) return;
  float l0 = hb[0], l1 = hb[1];
  for (int pos = 0; pos < 9; pos++) {
#pragma unroll
    for (int cb = 0; cb < 8; cb++) {
      bf16x8 v8 = *(const bf16x8*)(h5 + ((size_t)pos * Bc + b) * 64 + cb * 8);
#pragma unroll
      for (int j = 0; j < 8; j++) {
        float v = bf2f((unsigned short)v8[j]);
        int f = (cb * 8 + j) * 9 + pos;
        l0 = fmaf(v, hw[f], l0);
        l1 = fmaf(v, hw[584 + f], l1);
      }
    }
  }
#pragma unroll
  for (int k = 0; k < 8; k++) {
    float v = info[(size_t)(bstart + b) * 8 + k];
    l0 = fmaf(v, hw[576 + k], l0);
    l1 = fmaf(v, hw[584 + 576 + k], l1);
  }
  float m = fmaxf(l0, l1);
  float e0 = __expf(l0 - m), e1 = __expf(l1 - m);
  float s = e0 + e1;
  out[(size_t)(bstart + b) * 2 + 0] = e0 / s;
  out[(size_t)(bstart + b) * 2 + 1] = e1 / s;
}

// ---------------------------------------------------------------------------

extern "C" void kernel_launch(void* const* d_in, const int* in_sizes, int n_in,
                              void* d_out, int out_size, void* d_ws, size_t ws_size,
                              hipStream_t stream) {
  const float* x = (const float*)d_in[0];
  const float* info = (const float*)d_in[1];
  const float* w1 = (const float*)d_in[2];
  const float* b1 = (const float*)d_in[3];
  const float* w2a = (const float*)d_in[4];
  const float* b2a = (const float*)d_in[5];
  const float* w2b = (const float*)d_in[6];
  const float* b2b = (const float*)d_in[7];
  const float* lw3 = (const float*)d_in[8];
  const float* lb3 = (const float*)d_in[9];
  const float* lw4 = (const float*)d_in[10];
  const float* lb4 = (const float*)d_in[11];
  const float* lw5 = (const float*)d_in[12];
  const float* lb5 = (const float*)d_in[13];
  const float* hw = (const float*)d_in[14];
  const float* hb = (const float*)d_in[15];
  float* out = (float*)d_out;

  const int B = in_sizes[0] / 18000;  // 2048

  // packed weights at ws start
  const size_t SZ2A = 9ull * 2048, SZ2B = 18ull * 2048, SZ3 = 81ull * 50 * 2048,
               SZ4 = 25ull * 50 * 2048, SZ5 = 9ull * 18 * 2048;
  unsigned short* wp2a = (unsigned short*)d_ws;
  unsigned short* wp2b = wp2a + SZ2A;
  unsigned short* wp3 = wp2b + SZ2B;
  unsigned short* wp4 = wp3 + SZ3;
  unsigned short* wp5 = wp4 + SZ4;
  size_t wp_bytes = (SZ2A + SZ2B + SZ3 + SZ4 + SZ5) * 2;
  wp_bytes = (wp_bytes + 255) & ~(size_t)255;
  float* w1t = (float*)((char*)d_ws + wp_bytes);
  size_t w1t_bytes = ((45 * 32 * 4) + 255) & ~(size_t)255;

  // per-sample: bufA bf16 53824B, bufB bf16 93312B
  const size_t PSA = 53824, PSB = 93312;
  const size_t per_sample = PSA + PSB;
  int Bc = B;
  while (Bc > 256 && wp_bytes + w1t_bytes + (size_t)Bc * per_sample + 4096 > ws_size)
    Bc >>= 1;

  char* base = (char*)d_ws + wp_bytes + w1t_bytes;
  unsigned short* bufA = (unsigned short*)base;
  unsigned short* bufB = (unsigned short*)(base + (size_t)Bc * PSA);

  // one-time weight packing (deterministic each launch)
  hipLaunchKernelGGL(pack_w1t, dim3(6), dim3(THREADS), 0, stream, w1, w1t);
  hipLaunchKernelGGL((pack_w<32, 3>), dim3((SZ2A + 255) / 256), dim3(THREADS), 0, stream,
                     w2a, wp2a, 1);
  hipLaunchKernelGGL((pack_w<64, 3>), dim3((SZ2B + 255) / 256), dim3(THREADS), 0, stream,
                     w2b, wp2b, 1);
  hipLaunchKernelGGL((pack_w<64, 5>), dim3((SZ3 + 255) / 256), dim3(THREADS), 0, stream,
                     lw3, wp3, 81);
  hipLaunchKernelGGL((pack_w<64, 5>), dim3((SZ4 + 255) / 256), dim3(THREADS), 0, stream,
                     lw4, wp4, 25);
  hipLaunchKernelGGL((pack_w<64, 3>), dim3((SZ5 + 255) / 256), dim3(THREADS), 0, stream,
                     lw5, wp5, 9);

  const int nchunks = B / Bc;
  for (int c = 0; c < nchunks; c++) {
    const int bstart = c * Bc;

    // conv1: 5->32, 60x60 -> 29x29, k3 s2
    hipLaunchKernelGGL(conv1_direct, dim3(Bc * 15), dim3(256), 0, stream, x, w1t, b1,
                       bufA, Bc, bstart);
    // conv2a: 32->64, 29x29 -> 27x27, k3 s1 — BW=2, NJ=8 (256 b/block)
    hipLaunchKernelGGL((conv_mfma<32, 29, 29, 27, 27, 3, 1, false, 2, 8>),
                       dim3(729 * (Bc / 256)), dim3(256), 0, stream, bufA, wp2a, b2a,
                       bufB, Bc);
    // conv2b: 64->64, 27x27 -> 13x13, k3 s2 — BW=2, NJ=8
    hipLaunchKernelGGL((conv_mfma<64, 27, 27, 13, 13, 3, 2, false, 2, 8>),
                       dim3(169 * (Bc / 256)), dim3(256), 0, stream, bufB, wp2b, b2b,
                       bufA, Bc);
    // local3: 64->64, 13x13 -> 9x9, k5 — BW=2, NJ=4 (128 b/block)
    hipLaunchKernelGGL((conv_mfma<64, 13, 13, 9, 9, 5, 1, true, 2, 4>),
                       dim3(81 * (Bc / 128)), dim3(256), 0, stream, bufA, wp3, lb3, bufB,
                       Bc);
    // local4: 64->64, 9x9 -> 5x5, k5 — BW=1, NJ=4 (64 b/block)
    hipLaunchKernelGGL((conv_mfma<64, 9, 9, 5, 5, 5, 1, true, 1, 4>),
                       dim3(25 * (Bc / 64)), dim3(256), 0, stream, bufB, wp4, lb4, bufA,
                       Bc);
    // local5: 64->64, 5x5 -> 3x3, k3 — BW=1, NJ=2 (32 b/block)
    hipLaunchKernelGGL((conv_mfma<64, 5, 5, 3, 3, 3, 1, true, 1, 2>),
                       dim3(9 * (Bc / 32)), dim3(256), 0, stream, bufA, wp5, lb5, bufB,
                       Bc);
    // head
    hipLaunchKernelGGL(head_k, dim3((Bc + THREADS - 1) / THREADS), dim3(THREADS), 0,
                       stream, bufB, info, hw, hb, out, Bc, bstart);
  }
}

// Round 13
// 537.646 us; speedup vs baseline: 1.3708x; 1.3708x over previous
//
#include <hip/hip_runtime.h>
#include <stdint.h>

#define THREADS 256

typedef short bf16x8 __attribute__((ext_vector_type(8)));
typedef float f32x4 __attribute__((ext_vector_type(4)));
typedef unsigned uint2_ __attribute__((ext_vector_type(2)));

#define GPTR(x) ((const __attribute__((address_space(1))) void*)(x))
#define LPTR(x) ((__attribute__((address_space(3))) void*)(x))

__device__ __forceinline__ unsigned short f2bf(float v) {
  unsigned u = __builtin_bit_cast(unsigned, v);
  u = (u + 0x7fff + ((u >> 16) & 1)) >> 16;
  return (unsigned short)u;
}
__device__ __forceinline__ float bf2f(unsigned short h) {
  return __builtin_bit_cast(float, (unsigned)h << 16);
}
__device__ __forceinline__ float fast_tanh(float x) {
  return 1.f - 2.f / (__expf(2.f * x) + 1.f);
}

__device__ __forceinline__ int xcd_swizzle(int wg, int nwg) {
  const int q = nwg >> 3, rr = nwg & 7;
  const int xcd = wg & 7, l = wg >> 3;
  return (xcd < rr ? xcd * (q + 1) : rr * (q + 1) + (xcd - rr) * q) + l;
}

// ---------------------------------------------------------------------------
// w1 transpose: (32, 45) -> (45, 32) fp32, for wave-uniform scalar loads.
// ---------------------------------------------------------------------------
__global__ void pack_w1t(const float* __restrict__ w1, float* __restrict__ w1t) {
  int idx = blockIdx.x * THREADS + threadIdx.x;
  if (idx >= 45 * 32) return;
  int t = idx >> 5, co = idx & 31;
  w1t[t * 32 + co] = w1[co * 45 + t];
}

// ---------------------------------------------------------------------------
// conv1 fused: x NCHW f32 -> out (29*29, Bc, 32) bf16, k3 s2, tanh.
// Block = 2 oh-rows of one sample. Wave = co-octet (weights wave-uniform),
// lane = position, acc[8] in VGPRs.
// ---------------------------------------------------------------------------
__global__ void __launch_bounds__(256) conv1_direct(
    const float* __restrict__ x, const float* __restrict__ w1t,
    const float* __restrict__ bias, unsigned short* __restrict__ out, int Bc,
    int bstart) {
  constexpr int CI = 5, CO = 32, IH = 60, IW = 60, OH = 29, OW = 29;
  constexpr int RPB = 2, NRB = 15;

  __shared__ float xs[CI * 5 * 60];  // 6000 B

  const int tid = threadIdx.x;
  const int b = blockIdx.x / NRB;
  const int qb = blockIdx.x % NRB;
  const int oh0 = qb * RPB;
  const int rows = min(RPB, OH - oh0);
  const int ih0 = oh0 * 2;
  const int ihn = rows * 2 + 1;

  const float* xp = x + (size_t)(bstart + b) * (CI * IH * IW);

  const int nf4 = CI * ihn * 15;
  for (int i = tid; i < nf4; i += 256) {
    int col = i % 15;
    int row = i / 15;
    int ci = row / ihn, r = row % ihn;
    ((float4*)xs)[row * 15 + col] = ((const float4*)xp)[(ci * IH + ih0 + r) * 15 + col];
  }
  __syncthreads();

  const int lane = tid & 63;
  const int wu = __builtin_amdgcn_readfirstlane(tid >> 6);
  if (lane >= rows * OW) return;
  const int r = lane / OW, c = lane % OW;
  const int base = (r * 2) * 60 + c * 2;
  const int cstr = ihn * 60;

  float acc[8];
#pragma unroll
  for (int j = 0; j < 8; j++) acc[j] = bias[wu * 8 + j];

#pragma unroll
  for (int ci = 0; ci < CI; ci++)
#pragma unroll
    for (int kh = 0; kh < 3; kh++)
#pragma unroll
      for (int kw = 0; kw < 3; kw++) {
        const float v = xs[ci * cstr + base + kh * 60 + kw];
        const float* wt = w1t + ((ci * 3 + kh) * 3 + kw) * 32 + wu * 8;
#pragma unroll
        for (int j = 0; j < 8; j++) acc[j] = fmaf(v, wt[j], acc[j]);
      }

  const int p = (oh0 + r) * OW + c;
  bf16x8 o;
#pragma unroll
  for (int j = 0; j < 8; j++) o[j] = (short)f2bf(fast_tanh(acc[j]));
  *(bf16x8*)(out + ((size_t)p * Bc + b) * CO + wu * 8) = o;
}

// ---------------------------------------------------------------------------
// Weight pre-pack into MFMA A-fragment order (bf16).
// dst wp: flat[pos][s][mt][lane][e], value = W[co=mt*16+(lane&15)]
//                                          [k = s*32 + (lane>>4)*8 + e]
// k-order: k = (kh*KS+kw)*CI + ci  (ci innermost).
// ---------------------------------------------------------------------------
template <int CI, int KS>
__global__ void __launch_bounds__(THREADS) pack_w(const float* __restrict__ w,
                                                  unsigned short* __restrict__ wp,
                                                  int npos) {
  constexpr int K = CI * KS * KS;
  constexpr int S = K / 32;
  int idx = blockIdx.x * THREADS + threadIdx.x;
  int total = npos * S * 2048;
  if (idx >= total) return;
  int e = idx & 7;
  int lane = (idx >> 3) & 63;
  int mt = (idx >> 9) & 3;
  int rest = idx >> 11;  // pos*S + s
  int s = rest % S, pos = rest / S;
  int co = mt * 16 + (lane & 15);
  int k = s * 32 + (lane >> 4) * 8 + e;
  int tap = k / CI, ci = k % CI;
  int kh = tap / KS, kw = tap % KS;
  float v = w[((((size_t)pos * 64 + co) * CI + ci) * KS + kh) * KS + kw];
  wp[idx] = f2bf(v);
}

// ---------------------------------------------------------------------------
// MFMA conv v7 — m97 structure: BOTH operands staged per K-step into
// double-buffered LDS via global_load_lds (linear dest), one barrier/step,
// ds_read_b128 fragments, MFMA. Block = 4 waves, each 64 co x NJ*16 batch.
// X: (IH*IW, Bc, CI)  Wp: packed  Y: (OH*OW, Bc, 64)
// Dense: pos-minor grid (X L2 locality); local: pos-major (W L2 locality).
// ---------------------------------------------------------------------------
template <int CI, int IH, int IW, int OH, int OW, int KS, int ST, bool LOCAL, int BT>
__global__ void __launch_bounds__(256) conv_mfma(
    const unsigned short* __restrict__ X, const unsigned short* __restrict__ Wp,
    const float* __restrict__ bias, unsigned short* __restrict__ Y, int Bc) {
  constexpr int S = CI * KS * KS / 32;
  constexpr int NPOS = OH * OW;
  constexpr int NJ = BT / 64;       // 16-batch groups per wave
  constexpr int NB = BT / 64;       // 4KB B-stage instructions per step

  __shared__ unsigned short As[2][2048];      // 2 x 4 KB
  __shared__ unsigned short Bs[2][BT * 32];   // 2 x BT*64 B

  const int tid = threadIdx.x;
  const int lane = tid & 63;
  const int wu = tid >> 6;
  const int n = lane & 15, g = lane >> 4;

  const int nbt = Bc / BT;
  int wg = xcd_swizzle(blockIdx.x, gridDim.x);
  int pos, btile;
  if (LOCAL) {  // pos-major: same-pos blocks contiguous -> W L2 locality
    btile = wg % nbt;
    pos = wg / nbt;
  } else {  // pos-minor: neighbor-pos blocks contiguous -> X L2 locality
    pos = wg % NPOS;
    btile = wg / NPOS;
  }
  const int oh = pos / OW, ow = pos % OW;
  const int b0 = btile * BT;

  const unsigned short* Wpp = Wp + (LOCAL ? (size_t)pos * (S * 2048) : 0);

  // B-stage thread mapping: thread stages 16B: row = i*64 + (tid>>2),
  // col8 = (tid&3)*8 elements of the 32-k slice.
  const int srow = tid >> 2;
  const int scol = (tid & 3) * 8;

  auto stage = [&](int s, int buf) {
    __builtin_amdgcn_global_load_lds(GPTR(Wpp + s * 2048 + tid * 8),
                                     LPTR(&As[buf][tid * 8]), 16, 0, 0);
    const int tap = (s * 32) / CI;
    const int ci0 = (s * 32) % CI;
    const int kh = tap / KS, kw = tap % KS;
    const int pin = (oh * ST + kh) * IW + (ow * ST + kw);
    const size_t base = (size_t)pin * Bc + b0;
#pragma unroll
    for (int i = 0; i < NB; i++)
      __builtin_amdgcn_global_load_lds(
          GPTR(X + (base + i * 64 + srow) * CI + ci0 + scol),
          LPTR(&Bs[buf][i * 2048 + tid * 8]), 16, 0, 0);
  };

  f32x4 acc[4][NJ] = {};

  stage(0, 0);
  int buf = 0;
  for (int s = 0; s < S; s++) {
    __syncthreads();  // drains stage(s); prev ds_reads done
    if (s + 1 < S) stage(s + 1, buf ^ 1);

    bf16x8 bfr[NJ];
#pragma unroll
    for (int j = 0; j < NJ; j++) {
      const int local_b = wu * (NJ * 16) + j * 16 + n;
      bfr[j] = *(const bf16x8*)(&Bs[buf][local_b * 32 + g * 8]);
    }
    bf16x8 af[4];
#pragma unroll
    for (int mt = 0; mt < 4; mt++)
      af[mt] = *(const bf16x8*)(&As[buf][(mt * 64 + lane) * 8]);

#pragma unroll
    for (int mt = 0; mt < 4; mt++)
#pragma unroll
      for (int j = 0; j < NJ; j++)
        acc[mt][j] =
            __builtin_amdgcn_mfma_f32_16x16x32_bf16(af[mt], bfr[j], acc[mt][j], 0, 0, 0);
    buf ^= 1;
  }

  // epilogue: D col=lane&15 (batch), row=(lane>>4)*4+reg (co)
#pragma unroll
  for (int mt = 0; mt < 4; mt++) {
#pragma unroll
    for (int j = 0; j < NJ; j++) {
      unsigned short o[4];
#pragma unroll
      for (int r = 0; r < 4; r++) {
        const int co = mt * 16 + g * 4 + r;
        o[r] = f2bf(fast_tanh(acc[mt][j][r] +
                              (LOCAL ? bias[pos * 64 + co] : bias[co])));
      }
      const int b = b0 + wu * (NJ * 16) + j * 16 + n;
      uint2_ pk;
      pk[0] = (unsigned)o[0] | ((unsigned)o[1] << 16);
      pk[1] = (unsigned)o[2] | ((unsigned)o[3] << 16);
      *(uint2_*)(Y + ((size_t)pos * Bc + b) * 64 + mt * 16 + g * 4) = pk;
    }
  }
}

// ---------------------------------------------------------------------------
// Head: h5 (9, Bc, 64) bf16; f = co*9 + pos. concat info(8), linear, softmax.
// ---------------------------------------------------------------------------
__global__ void head_k(const unsigned short* __restrict__ h5,
                       const float* __restrict__ info, const float* __restrict__ hw,
                       const float* __restrict__ hb, float* __restrict__ out, int Bc,
                       int bstart) {
  int b = blockIdx.x * THREADS + threadIdx.x;
  if (b >= Bc) return;
  float l0 = hb[0], l1 = hb[1];
  for (int pos = 0; pos < 9; pos++) {
#pragma unroll
    for (int cb = 0; cb < 8; cb++) {
      bf16x8 v8 = *(const bf16x8*)(h5 + ((size_t)pos * Bc + b) * 64 + cb * 8);
#pragma unroll
      for (int j = 0; j < 8; j++) {
        float v = bf2f((unsigned short)v8[j]);
        int f = (cb * 8 + j) * 9 + pos;
        l0 = fmaf(v, hw[f], l0);
        l1 = fmaf(v, hw[584 + f], l1);
      }
    }
  }
#pragma unroll
  for (int k = 0; k < 8; k++) {
    float v = info[(size_t)(bstart + b) * 8 + k];
    l0 = fmaf(v, hw[576 + k], l0);
    l1 = fmaf(v, hw[584 + 576 + k], l1);
  }
  float m = fmaxf(l0, l1);
  float e0 = __expf(l0 - m), e1 = __expf(l1 - m);
  float s = e0 + e1;
  out[(size_t)(bstart + b) * 2 + 0] = e0 / s;
  out[(size_t)(bstart + b) * 2 + 1] = e1 / s;
}

// ---------------------------------------------------------------------------

extern "C" void kernel_launch(void* const* d_in, const int* in_sizes, int n_in,
                              void* d_out, int out_size, void* d_ws, size_t ws_size,
                              hipStream_t stream) {
  const float* x = (const float*)d_in[0];
  const float* info = (const float*)d_in[1];
  const float* w1 = (const float*)d_in[2];
  const float* b1 = (const float*)d_in[3];
  const float* w2a = (const float*)d_in[4];
  const float* b2a = (const float*)d_in[5];
  const float* w2b = (const float*)d_in[6];
  const float* b2b = (const float*)d_in[7];
  const float* lw3 = (const float*)d_in[8];
  const float* lb3 = (const float*)d_in[9];
  const float* lw4 = (const float*)d_in[10];
  const float* lb4 = (const float*)d_in[11];
  const float* lw5 = (const float*)d_in[12];
  const float* lb5 = (const float*)d_in[13];
  const float* hw = (const float*)d_in[14];
  const float* hb = (const float*)d_in[15];
  float* out = (float*)d_out;

  const int B = in_sizes[0] / 18000;  // 2048

  // packed weights at ws start
  const size_t SZ2A = 9ull * 2048, SZ2B = 18ull * 2048, SZ3 = 81ull * 50 * 2048,
               SZ4 = 25ull * 50 * 2048, SZ5 = 9ull * 18 * 2048;
  unsigned short* wp2a = (unsigned short*)d_ws;
  unsigned short* wp2b = wp2a + SZ2A;
  unsigned short* wp3 = wp2b + SZ2B;
  unsigned short* wp4 = wp3 + SZ3;
  unsigned short* wp5 = wp4 + SZ4;
  size_t wp_bytes = (SZ2A + SZ2B + SZ3 + SZ4 + SZ5) * 2;
  wp_bytes = (wp_bytes + 255) & ~(size_t)255;
  float* w1t = (float*)((char*)d_ws + wp_bytes);
  size_t w1t_bytes = ((45 * 32 * 4) + 255) & ~(size_t)255;

  // per-sample: bufA bf16 53824B, bufB bf16 93312B
  const size_t PSA = 53824, PSB = 93312;
  const size_t per_sample = PSA + PSB;
  int Bc = B;
  while (Bc > 256 && wp_bytes + w1t_bytes + (size_t)Bc * per_sample + 4096 > ws_size)
    Bc >>= 1;

  char* base = (char*)d_ws + wp_bytes + w1t_bytes;
  unsigned short* bufA = (unsigned short*)base;
  unsigned short* bufB = (unsigned short*)(base + (size_t)Bc * PSA);

  // one-time weight packing (deterministic each launch)
  hipLaunchKernelGGL(pack_w1t, dim3(6), dim3(THREADS), 0, stream, w1, w1t);
  hipLaunchKernelGGL((pack_w<32, 3>), dim3((SZ2A + 255) / 256), dim3(THREADS), 0, stream,
                     w2a, wp2a, 1);
  hipLaunchKernelGGL((pack_w<64, 3>), dim3((SZ2B + 255) / 256), dim3(THREADS), 0, stream,
                     w2b, wp2b, 1);
  hipLaunchKernelGGL((pack_w<64, 5>), dim3((SZ3 + 255) / 256), dim3(THREADS), 0, stream,
                     lw3, wp3, 81);
  hipLaunchKernelGGL((pack_w<64, 5>), dim3((SZ4 + 255) / 256), dim3(THREADS), 0, stream,
                     lw4, wp4, 25);
  hipLaunchKernelGGL((pack_w<64, 3>), dim3((SZ5 + 255) / 256), dim3(THREADS), 0, stream,
                     lw5, wp5, 9);

  const int nchunks = B / Bc;
  for (int c = 0; c < nchunks; c++) {
    const int bstart = c * Bc;

    // conv1: 5->32, 60x60 -> 29x29, k3 s2
    hipLaunchKernelGGL(conv1_direct, dim3(Bc * 15), dim3(256), 0, stream, x, w1t, b1,
                       bufA, Bc, bstart);
    // conv2a: 32->64, 29x29 -> 27x27, k3 s1 — BT=256
    hipLaunchKernelGGL((conv_mfma<32, 29, 29, 27, 27, 3, 1, false, 256>),
                       dim3(729 * (Bc / 256)), dim3(256), 0, stream, bufA, wp2a, b2a,
                       bufB, Bc);
    // conv2b: 64->64, 27x27 -> 13x13, k3 s2 — BT=256
    hipLaunchKernelGGL((conv_mfma<64, 27, 27, 13, 13, 3, 2, false, 256>),
                       dim3(169 * (Bc / 256)), dim3(256), 0, stream, bufB, wp2b, b2b,
                       bufA, Bc);
    // local3: 64->64, 13x13 -> 9x9, k5 — BT=256
    hipLaunchKernelGGL((conv_mfma<64, 13, 13, 9, 9, 5, 1, true, 256>),
                       dim3(81 * (Bc / 256)), dim3(256), 0, stream, bufA, wp3, lb3, bufB,
                       Bc);
    // local4: 64->64, 9x9 -> 5x5, k5 — BT=128
    hipLaunchKernelGGL((conv_mfma<64, 9, 9, 5, 5, 5, 1, true, 128>),
                       dim3(25 * (Bc / 128)), dim3(256), 0, stream, bufB, wp4, lb4, bufA,
                       Bc);
    // local5: 64->64, 5x5 -> 3x3, k3 — BT=128
    hipLaunchKernelGGL((conv_mfma<64, 5, 5, 3, 3, 3, 1, true, 128>),
                       dim3(9 * (Bc / 128)), dim3(256), 0, stream, bufA, wp5, lb5, bufB,
                       Bc);
    // head
    hipLaunchKernelGGL(head_k, dim3((Bc + THREADS - 1) / THREADS), dim3(THREADS), 0,
                       stream, bufB, info, hw, hb, out, Bc, bstart);
  }
}